// Round 3
// baseline (1371.870 us; speedup 1.0000x reference)
//
#include <hip/hip_runtime.h>
#include <math.h>

constexpr int NNODES  = 102400;
constexpr int NEDGES  = 409600;
constexpr int NGRAPHS = 2048;
constexpr int HIDDEN  = 128;

__device__ __forceinline__ float relu_f(float v) { return fmaxf(v, 0.0f); }

// ---------------- histogram ----------------
__global__ void hist_kernel(const int* __restrict__ idx, int n, int* __restrict__ counts) {
  int i = blockIdx.x * blockDim.x + threadIdx.x;
  if (i < n) atomicAdd(&counts[idx[i]], 1);
}

// ---------------- scans (exclusive prefix over counts) ----------------
__global__ void scan_block_kernel(const int* __restrict__ in, int n,
                                  int* __restrict__ out_excl, int* __restrict__ bsums) {
  __shared__ int s[256];
  int t = threadIdx.x;
  int i = blockIdx.x * 256 + t;
  int v = (i < n) ? in[i] : 0;
  s[t] = v;
  __syncthreads();
  for (int off = 1; off < 256; off <<= 1) {
    int x = (t >= off) ? s[t - off] : 0;
    __syncthreads();
    s[t] += x;
    __syncthreads();
  }
  if (i < n) out_excl[i] = s[t] - v;
  if (t == 255) bsums[blockIdx.x] = s[255];
}

__global__ void scan_top_kernel(int* __restrict__ bsums, int nb) {
  __shared__ int s[1024];
  int t = threadIdx.x;
  int v = (t < nb) ? bsums[t] : 0;
  s[t] = v;
  __syncthreads();
  for (int off = 1; off < 1024; off <<= 1) {
    int x = (t >= off) ? s[t - off] : 0;
    __syncthreads();
    s[t] += x;
    __syncthreads();
  }
  if (t < nb) bsums[t] = s[t] - v;
  if (t == 1023) bsums[nb] = s[1023];  // total
}

__global__ void scan_add_kernel(int* __restrict__ arr, const int* __restrict__ bsums,
                                int n, int* __restrict__ nextcopy) {
  int i = blockIdx.x * 256 + threadIdx.x;
  if (i < n) {
    int v = arr[i] + bsums[blockIdx.x];
    arr[i] = v;
    if (nextcopy) nextcopy[i] = v;
  }
  if (i == 0) arr[n] = bsums[gridDim.x];
}

__global__ void scatter_kernel(const int* __restrict__ ei, int* __restrict__ nxt,
                               int* __restrict__ csr_src) {
  int e = blockIdx.x * blockDim.x + threadIdx.x;
  if (e < NEDGES) {
    int s = ei[e];            // src row
    int d = ei[NEDGES + e];   // dst row
    int pos = atomicAdd(&nxt[d], 1);
    csr_src[pos] = s;
  }
}

// ---------------- fused GIN layer ----------------
// 512 threads, 32-row tile: agg(+prev-BN-relu) -> LDS(T) -> relu(h@W1+b1)@W2+b2 -> O + BN partials
// launch_bounds(512,8): 8 waves/EU -> 4 blocks/CU -> 32 waves/CU for gather-latency hiding
template<int DIN, bool XF>
__global__ __launch_bounds__(512, 8) void gin_kernel(
    const float* __restrict__ X,
    const int* __restrict__ row_ptr, const int* __restrict__ csr_src,
    const float* __restrict__ W1, const float* __restrict__ b1,
    const float* __restrict__ W2, const float* __restrict__ b2,
    const float* __restrict__ scale, const float* __restrict__ shift,
    float* __restrict__ O, float* __restrict__ bn_sum, float* __restrict__ bn_sq) {
  constexpr int R = 32, STR = R + 4;           // pad 36 keeps b128 reads 16B-aligned
  __shared__ __align__(16) float xT[DIN * STR];     // [k][r]
  __shared__ __align__(16) float mT[HIDDEN * STR];  // [j][r]
  const int t = threadIdx.x;
  const int wv = t >> 6, lane = t & 63;
  const int base = blockIdx.x * R;

  // ---- aggregation: each of 8 waves handles 4 rows; lane holds features 2*lane, 2*lane+1
  {
    const int f0 = 2 * lane, f1 = 2 * lane + 1;
    if (f0 < DIN) {
      float sc0 = 1.f, sh0 = 0.f, sc1 = 1.f, sh1 = 0.f;
      if (XF) { sc0 = scale[f0]; sh0 = shift[f0]; sc1 = scale[f1]; sh1 = shift[f1]; }
      for (int rr = 0; rr < 4; ++rr) {
        const int r = wv * 4 + rr;
        const int node = base + r;
        const float2 v = *(const float2*)&X[(long)node * DIN + f0];
        float a0 = XF ? relu_f(fmaf(v.x, sc0, sh0)) : v.x;
        float a1 = XF ? relu_f(fmaf(v.y, sc1, sh1)) : v.y;
        const int e0 = row_ptr[node], e1 = row_ptr[node + 1];
        for (int e = e0; e < e1; ++e) {
          const float2 u = *(const float2*)&X[(long)csr_src[e] * DIN + f0];
          a0 += XF ? relu_f(fmaf(u.x, sc0, sh0)) : u.x;
          a1 += XF ? relu_f(fmaf(u.y, sc1, sh1)) : u.y;
        }
        xT[f0 * STR + r] = a0;
        xT[f1 * STR + r] = a1;
      }
    }
  }
  __syncthreads();

  const int rg = t >> 6, cg = t & 63;     // 8 row-groups x 64 col-groups
  const int r0 = rg * 4, j0 = cg * 2;     // 4x2 tile per thread

  // ---- mm1: mid = relu(h @ W1 + b1), stored transposed in mT
  {
    float acc[4][2];
    const float2 bb = *(const float2*)&b1[j0];
    for (int r = 0; r < 4; ++r) { acc[r][0] = bb.x; acc[r][1] = bb.y; }
    for (int k = 0; k < DIN; ++k) {
      const float2 w = *(const float2*)&W1[k * HIDDEN + j0];
      const float4 x = *(const float4*)&xT[k * STR + r0];
      const float xa[4] = {x.x, x.y, x.z, x.w};
      for (int r = 0; r < 4; ++r) {
        acc[r][0] = fmaf(xa[r], w.x, acc[r][0]);
        acc[r][1] = fmaf(xa[r], w.y, acc[r][1]);
      }
    }
    for (int c = 0; c < 2; ++c) {
      float4 m = { relu_f(acc[0][c]), relu_f(acc[1][c]), relu_f(acc[2][c]), relu_f(acc[3][c]) };
      *(float4*)&mT[(j0 + c) * STR + r0] = m;
    }
  }
  __syncthreads();

  // ---- mm2: o = mid @ W2 + b2; store pre-BN + BN partials
  float csum[2] = {0, 0}, csq[2] = {0, 0};
  {
    float acc[4][2];
    const float2 bb = *(const float2*)&b2[j0];
    for (int r = 0; r < 4; ++r) { acc[r][0] = bb.x; acc[r][1] = bb.y; }
    for (int k = 0; k < HIDDEN; ++k) {
      const float2 w = *(const float2*)&W2[k * HIDDEN + j0];
      const float4 x = *(const float4*)&mT[k * STR + r0];
      const float xa[4] = {x.x, x.y, x.z, x.w};
      for (int r = 0; r < 4; ++r) {
        acc[r][0] = fmaf(xa[r], w.x, acc[r][0]);
        acc[r][1] = fmaf(xa[r], w.y, acc[r][1]);
      }
    }
    for (int r = 0; r < 4; ++r) {
      float2 o = { acc[r][0], acc[r][1] };
      *(float2*)&O[(long)(base + r0 + r) * HIDDEN + j0] = o;
      for (int c = 0; c < 2; ++c) {
        csum[c] += acc[r][c];
        csq[c] = fmaf(acc[r][c], acc[r][c], csq[c]);
      }
    }
  }
  __syncthreads();  // all mm reads done -> xT reusable as scratch
  for (int c = 0; c < 2; ++c) {
    xT[(j0 + c) * 8 + rg] = csum[c];
    xT[1024 + (j0 + c) * 8 + rg] = csq[c];
  }
  __syncthreads();
  if (t < HIDDEN) {
    float s = 0.f, q = 0.f;
    for (int g = 0; g < 8; ++g) { s += xT[t * 8 + g]; q += xT[1024 + t * 8 + g]; }
    atomicAdd(&bn_sum[t], s);
    atomicAdd(&bn_sq[t], q);
  }
}

__global__ void bn_finalize_kernel(const float* __restrict__ bn_sum, const float* __restrict__ bn_sq,
                                   const float* __restrict__ g, const float* __restrict__ b,
                                   float* __restrict__ scale, float* __restrict__ shift) {
  int j = threadIdx.x;
  float mu  = bn_sum[j] * (1.0f / NNODES);
  float var = fmaxf(bn_sq[j] * (1.0f / NNODES) - mu * mu, 0.0f);
  float sc  = g[j] / sqrtf(var + 1e-5f);
  scale[j] = sc;
  shift[j] = b[j] - mu * sc;
}

// ---------------- global add pool (with final BN+relu fold) ----------------
__global__ __launch_bounds__(256) void pool_kernel(const float* __restrict__ O,
    const int* __restrict__ gp, const float* __restrict__ scale, const float* __restrict__ shift,
    float* __restrict__ P) {
  int t = threadIdx.x;
  int g = blockIdx.x * 4 + (t >> 6);
  int lane = t & 63;
  int f0 = lane, f1 = lane + 64;
  float sc0 = scale[f0], sh0 = shift[f0], sc1 = scale[f1], sh1 = shift[f1];
  int n0 = gp[g], n1 = gp[g + 1];
  float a0 = 0.f, a1 = 0.f;
  for (int n = n0; n < n1; ++n) {
    a0 += relu_f(fmaf(O[(long)n * HIDDEN + f0], sc0, sh0));
    a1 += relu_f(fmaf(O[(long)n * HIDDEN + f1], sc1, sh1));
  }
  P[g * HIDDEN + f0] = a0;
  P[g * HIDDEN + f1] = a1;
}

// ---------------- protein conv1d(1->32,k=8) + relu + global max ----------------
__global__ __launch_bounds__(256) void conv_kernel(const float* __restrict__ PS,
    const float* __restrict__ CK, const float* __restrict__ CB, float* __restrict__ XP) {
  __shared__ float seq[1000];
  const int t = threadIdx.x, g = blockIdx.x;
  for (int i = t; i < 1000; i += 256) seq[i] = PS[g * 1000 + i];
  __syncthreads();
  const int pl = t & 31, cgp = t >> 5;   // 32 position lanes x 8 channel-groups(4 ch)
  float kr[4][8];
  for (int cc = 0; cc < 4; ++cc)
    for (int k = 0; k < 8; ++k) kr[cc][k] = CK[(cgp * 4 + cc) * 8 + k];
  float m[4] = {-1e30f, -1e30f, -1e30f, -1e30f};
  for (int i = 0; i < 32; ++i) {
    int p = pl + 32 * i;
    if (p < 993) {
      float sv[8];
      for (int k = 0; k < 8; ++k) sv[k] = seq[p + k];
      for (int cc = 0; cc < 4; ++cc) {
        float s = 0.f;
        for (int k = 0; k < 8; ++k) s = fmaf(sv[k], kr[cc][k], s);
        m[cc] = fmaxf(m[cc], s);
      }
    }
  }
  for (int off = 16; off >= 1; off >>= 1)
    for (int cc = 0; cc < 4; ++cc) m[cc] = fmaxf(m[cc], __shfl_xor(m[cc], off));
  if (pl == 0)
    for (int cc = 0; cc < 4; ++cc)
      XP[g * 32 + cgp * 4 + cc] = relu_f(m[cc] + CB[cgp * 4 + cc]);
}

// ---------------- tail gemm: C = relu(A@W + b), 16 rows x 64 cols per block ----------------
template<bool RELU_A>
__global__ __launch_bounds__(256) void gemm2_kernel(const float* __restrict__ A, int lda, int K,
    const float* __restrict__ W, int ldw, const float* __restrict__ bias,
    float* __restrict__ C, int ldc, int coff) {
  constexpr int RT = 16, CH = 64, STR = RT + 4;
  __shared__ __align__(16) float AT[CH * STR];
  const int t = threadIdx.x;
  const int rg = t >> 6, cg = t & 63;
  const int r0 = rg * 4;
  const int row0 = blockIdx.x * RT;
  const int col = blockIdx.y * 64 + cg;
  float a0 = 0.f, a1 = 0.f, a2 = 0.f, a3 = 0.f;
  for (int k0 = 0; k0 < K; k0 += CH) {
    const int kc = min(CH, K - k0);
    __syncthreads();
    for (int i = t; i < RT * CH; i += 256) {
      int kk = i & (CH - 1), r = i >> 6;
      if (kk < kc) {
        float v = A[(long)(row0 + r) * lda + k0 + kk];
        AT[kk * STR + r] = RELU_A ? relu_f(v) : v;
      }
    }
    __syncthreads();
    for (int kk = 0; kk < kc; ++kk) {
      const float4 x = *(const float4*)&AT[kk * STR + r0];
      const float w = W[(long)(k0 + kk) * ldw + col];
      a0 = fmaf(x.x, w, a0);
      a1 = fmaf(x.y, w, a1);
      a2 = fmaf(x.z, w, a2);
      a3 = fmaf(x.w, w, a3);
    }
  }
  const float bv = bias[col];
  C[(long)(row0 + r0 + 0) * ldc + coff + col] = relu_f(a0 + bv);
  C[(long)(row0 + r0 + 1) * ldc + coff + col] = relu_f(a1 + bv);
  C[(long)(row0 + r0 + 2) * ldc + coff + col] = relu_f(a2 + bv);
  C[(long)(row0 + r0 + 3) * ldc + coff + col] = relu_f(a3 + bv);
}

// ---------------- a2h branch: XA init with bias ----------------
__global__ __launch_bounds__(256) void bias_fill_kernel(const float* __restrict__ b,
                                                        float* __restrict__ XA) {
  int i = blockIdx.x * 256 + threadIdx.x;
  XA[i] = b[i & (HIDDEN - 1)];
}

// ---------------- a2h branch split-K gemm: XA += A@W (atomic), pre-relu ----------------
// A: 2048 x 3000, W: 3000 x 128. Grid: (2048/16) x 10 splits of 300.
constexpr int A2H_K = 3000, A2H_SPLIT = 300, A2H_NSPLIT = 10;
__global__ __launch_bounds__(128) void a2h_gemm_kernel(const float* __restrict__ A,
    const float* __restrict__ W, float* __restrict__ XA) {
  constexpr int RT = 16, STR = RT + 4;   // LDS tile [300][20]
  __shared__ __align__(16) float xT[A2H_SPLIT * STR];  // 24 KB
  const int t = threadIdx.x;
  const int row0 = blockIdx.x * RT;
  const int k0 = blockIdx.y * A2H_SPLIT;

  // stage A tile transposed: 16 rows x 300 k, coalesced float4 along k
  constexpr int Q = A2H_SPLIT / 4;       // 75 float4 per row
  for (int i = t; i < RT * Q; i += 128) {
    const int r = i / Q, kq = i - r * Q;
    const float4 v = *(const float4*)&A[(long)(row0 + r) * A2H_K + k0 + kq * 4];
    xT[(kq * 4 + 0) * STR + r] = v.x;
    xT[(kq * 4 + 1) * STR + r] = v.y;
    xT[(kq * 4 + 2) * STR + r] = v.z;
    xT[(kq * 4 + 3) * STR + r] = v.w;
  }
  __syncthreads();

  const int rg = t >> 5, cg = t & 31;    // 4 row-groups x 32 col-groups
  const int r0 = rg * 4, j0 = cg * 4;
  float acc[4][4];
  for (int r = 0; r < 4; ++r)
    for (int c = 0; c < 4; ++c) acc[r][c] = 0.f;

  const float* Wp = W + (long)k0 * HIDDEN + j0;
  for (int k = 0; k < A2H_SPLIT; ++k) {
    const float4 w = *(const float4*)&Wp[(long)k * HIDDEN];
    const float4 x = *(const float4*)&xT[k * STR + r0];
    const float xa[4] = {x.x, x.y, x.z, x.w};
    const float wa[4] = {w.x, w.y, w.z, w.w};
    for (int r = 0; r < 4; ++r)
      for (int c = 0; c < 4; ++c)
        acc[r][c] = fmaf(xa[r], wa[c], acc[r][c]);
  }
  for (int r = 0; r < 4; ++r)
    for (int c = 0; c < 4; ++c)
      atomicAdd(&XA[(long)(row0 + r0 + r) * HIDDEN + j0 + c], acc[r][c]);
}

// ---------------- final projection to scalar ----------------
__global__ __launch_bounds__(256) void final_dot_kernel(const float* __restrict__ X,
    const float* __restrict__ Wo, const float* __restrict__ bo, float* __restrict__ out) {
  int t = threadIdx.x;
  int g = blockIdx.x * 4 + (t >> 6);
  int lane = t & 63;
  float2 x = *(const float2*)&X[g * HIDDEN + lane * 2];
  float2 w = *(const float2*)&Wo[lane * 2];
  float p = x.x * w.x + x.y * w.y;
  for (int off = 32; off >= 1; off >>= 1) p += __shfl_down(p, off);
  if (lane == 0) out[g] = p + bo[0];
}

extern "C" void kernel_launch(void* const* d_in, const int* in_sizes, int n_in,
                              void* d_out, int out_size, void* d_ws, size_t ws_size,
                              hipStream_t stream) {
  const float* x_lig = (const float*)d_in[0];
  const float* pseq  = (const float*)d_in[1];
  const float* a2h   = (const float*)d_in[2];
  const int*   ei    = (const int*)d_in[3];
  const int*   batch = (const int*)d_in[4];
  const float* ginW1[3] = {(const float*)d_in[5],  (const float*)d_in[11], (const float*)d_in[17]};
  const float* ginb1[3] = {(const float*)d_in[6],  (const float*)d_in[12], (const float*)d_in[18]};
  const float* ginW2[3] = {(const float*)d_in[7],  (const float*)d_in[13], (const float*)d_in[19]};
  const float* ginb2[3] = {(const float*)d_in[8],  (const float*)d_in[14], (const float*)d_in[20]};
  const float* bng[3]   = {(const float*)d_in[9],  (const float*)d_in[15], (const float*)d_in[21]};
  const float* bnb[3]   = {(const float*)d_in[10], (const float*)d_in[16], (const float*)d_in[22]};
  const float* ligW  = (const float*)d_in[23]; const float* ligb  = (const float*)d_in[24];
  const float* convk = (const float*)d_in[25]; const float* convb = (const float*)d_in[26];
  const float* protW = (const float*)d_in[27]; const float* protb = (const float*)d_in[28];
  const float* a1W   = (const float*)d_in[29]; const float* a1b   = (const float*)d_in[30];
  const float* a2W   = (const float*)d_in[31]; const float* a2b   = (const float*)d_in[32];
  const float* c1W   = (const float*)d_in[33]; const float* c1b   = (const float*)d_in[34];
  const float* c2W   = (const float*)d_in[35]; const float* c2b   = (const float*)d_in[36];
  const float* oW    = (const float*)d_in[37]; const float* ob    = (const float*)d_in[38];

  char* base = (char*)d_ws;
  size_t off = 0;
  auto alloc = [&](size_t bytes) -> char* {
    char* p = base + off;
    off = (off + bytes + 511) & ~size_t(511);
    return p;
  };
  int*   counts  = (int*)alloc(NNODES * 4);
  int*   gcounts = (int*)alloc(NGRAPHS * 4);
  float* bn_sum  = (float*)alloc(3 * 128 * 4);
  float* bn_sq   = (float*)alloc(3 * 128 * 4);
  const size_t zero_bytes = off;          // counts+gcounts+bn accumulators
  float* bn_scale = (float*)alloc(3 * 128 * 4);
  float* bn_shift = (float*)alloc(3 * 128 * 4);
  int*   row_ptr  = (int*)alloc((NNODES + 1) * 4);
  int*   nxt      = (int*)alloc(NNODES * 4);
  int*   gptr     = (int*)alloc((NGRAPHS + 1) * 4);
  int*   bsumsA   = (int*)alloc(401 * 4);
  int*   bsumsB   = (int*)alloc(9 * 4);
  int*   csr_src  = (int*)alloc(NEDGES * 4);
  float* P        = (float*)alloc(NGRAPHS * 128 * 4);
  float* XA       = (float*)alloc(NGRAPHS * 128 * 4);
  float* XP32     = (float*)alloc(NGRAPHS * 32 * 4);
  float* XC       = (float*)alloc(NGRAPHS * 384 * 4);
  float* XC2      = (float*)alloc(NGRAPHS * 256 * 4);
  float* XC3      = (float*)alloc(NGRAPHS * 128 * 4);
  float* O0       = (float*)alloc((size_t)NNODES * 128 * 4);
  float* O1       = (float*)alloc((size_t)NNODES * 128 * 4);
  (void)ws_size; (void)in_sizes; (void)n_in; (void)out_size;

  hipMemsetAsync(d_ws, 0, zero_bytes, stream);

  // CSR over dst + graph segment ptrs (rebuilt every call; edges constant within a call)
  hist_kernel<<<(NEDGES + 255) / 256, 256, 0, stream>>>(ei + NEDGES, NEDGES, counts);
  hist_kernel<<<(NNODES + 255) / 256, 256, 0, stream>>>(batch, NNODES, gcounts);
  scan_block_kernel<<<NNODES / 256, 256, 0, stream>>>(counts, NNODES, row_ptr, bsumsA);
  scan_block_kernel<<<NGRAPHS / 256, 256, 0, stream>>>(gcounts, NGRAPHS, gptr, bsumsB);
  scan_top_kernel<<<1, 1024, 0, stream>>>(bsumsA, NNODES / 256);
  scan_top_kernel<<<1, 1024, 0, stream>>>(bsumsB, NGRAPHS / 256);
  scan_add_kernel<<<NNODES / 256, 256, 0, stream>>>(row_ptr, bsumsA, NNODES, nxt);
  scan_add_kernel<<<NGRAPHS / 256, 256, 0, stream>>>(gptr, bsumsB, NGRAPHS, nullptr);
  scatter_kernel<<<(NEDGES + 255) / 256, 256, 0, stream>>>(ei, nxt, csr_src);

  // a2h branch early (independent): bias fill + split-K atomic gemm
  bias_fill_kernel<<<NGRAPHS * HIDDEN / 256, 256, 0, stream>>>(a1b, XA);
  a2h_gemm_kernel<<<dim3(NGRAPHS / 16, A2H_NSPLIT), 128, 0, stream>>>(a2h, a1W, XA);

  // GIN layers (BN+relu of layer l folded into consumer of layer l)
  gin_kernel<78, false><<<NNODES / 32, 512, 0, stream>>>(x_lig, row_ptr, csr_src,
      ginW1[0], ginb1[0], ginW2[0], ginb2[0], nullptr, nullptr, O0, bn_sum, bn_sq);
  bn_finalize_kernel<<<1, 128, 0, stream>>>(bn_sum, bn_sq, bng[0], bnb[0], bn_scale, bn_shift);
  gin_kernel<128, true><<<NNODES / 32, 512, 0, stream>>>(O0, row_ptr, csr_src,
      ginW1[1], ginb1[1], ginW2[1], ginb2[1], bn_scale, bn_shift, O1, bn_sum + 128, bn_sq + 128);
  bn_finalize_kernel<<<1, 128, 0, stream>>>(bn_sum + 128, bn_sq + 128, bng[1], bnb[1],
                                            bn_scale + 128, bn_shift + 128);
  gin_kernel<128, true><<<NNODES / 32, 512, 0, stream>>>(O1, row_ptr, csr_src,
      ginW1[2], ginb1[2], ginW2[2], ginb2[2], bn_scale + 128, bn_shift + 128, O0,
      bn_sum + 256, bn_sq + 256);
  bn_finalize_kernel<<<1, 128, 0, stream>>>(bn_sum + 256, bn_sq + 256, bng[2], bnb[2],
                                            bn_scale + 256, bn_shift + 256);

  // branches
  pool_kernel<<<NGRAPHS / 4, 256, 0, stream>>>(O0, gptr, bn_scale + 256, bn_shift + 256, P);
  conv_kernel<<<NGRAPHS, 256, 0, stream>>>(pseq, convk, convb, XP32);
  gemm2_kernel<false><<<dim3(NGRAPHS / 16, 2), 256, 0, stream>>>(P, 128, 128, ligW, 128, ligb, XC, 384, 0);
  gemm2_kernel<false><<<dim3(NGRAPHS / 16, 2), 256, 0, stream>>>(XP32, 32, 32, protW, 128, protb, XC, 384, 128);
  gemm2_kernel<true><<<dim3(NGRAPHS / 16, 2), 256, 0, stream>>>(XA, 128, 128, a2W, 128, a2b, XC, 384, 256);

  // head
  gemm2_kernel<false><<<dim3(NGRAPHS / 16, 4), 256, 0, stream>>>(XC, 384, 384, c1W, 256, c1b, XC2, 256, 0);
  gemm2_kernel<false><<<dim3(NGRAPHS / 16, 2), 256, 0, stream>>>(XC2, 256, 256, c2W, 128, c2b, XC3, 128, 0);
  final_dot_kernel<<<NGRAPHS / 4, 256, 0, stream>>>(XC3, oW, ob, (float*)d_out);
}

// Round 4
// 993.749 us; speedup vs baseline: 1.3805x; 1.3805x over previous
//
#include <hip/hip_runtime.h>
#include <math.h>

constexpr int NNODES  = 102400;
constexpr int NEDGES  = 409600;
constexpr int NGRAPHS = 2048;
constexpr int HIDDEN  = 128;

__device__ __forceinline__ float relu_f(float v) { return fmaxf(v, 0.0f); }

// ---------------- histogram ----------------
__global__ void hist_kernel(const int* __restrict__ idx, int n, int* __restrict__ counts) {
  int i = blockIdx.x * blockDim.x + threadIdx.x;
  if (i < n) atomicAdd(&counts[idx[i]], 1);
}

// ---------------- scans (exclusive prefix over counts) ----------------
__global__ void scan_block_kernel(const int* __restrict__ in, int n,
                                  int* __restrict__ out_excl, int* __restrict__ bsums) {
  __shared__ int s[256];
  int t = threadIdx.x;
  int i = blockIdx.x * 256 + t;
  int v = (i < n) ? in[i] : 0;
  s[t] = v;
  __syncthreads();
  for (int off = 1; off < 256; off <<= 1) {
    int x = (t >= off) ? s[t - off] : 0;
    __syncthreads();
    s[t] += x;
    __syncthreads();
  }
  if (i < n) out_excl[i] = s[t] - v;
  if (t == 255) bsums[blockIdx.x] = s[255];
}

__global__ void scan_top_kernel(int* __restrict__ bsums, int nb) {
  __shared__ int s[1024];
  int t = threadIdx.x;
  int v = (t < nb) ? bsums[t] : 0;
  s[t] = v;
  __syncthreads();
  for (int off = 1; off < 1024; off <<= 1) {
    int x = (t >= off) ? s[t - off] : 0;
    __syncthreads();
    s[t] += x;
    __syncthreads();
  }
  if (t < nb) bsums[t] = s[t] - v;
  if (t == 1023) bsums[nb] = s[1023];  // total
}

__global__ void scan_add_kernel(int* __restrict__ arr, const int* __restrict__ bsums,
                                int n, int* __restrict__ nextcopy) {
  int i = blockIdx.x * 256 + threadIdx.x;
  if (i < n) {
    int v = arr[i] + bsums[blockIdx.x];
    arr[i] = v;
    if (nextcopy) nextcopy[i] = v;
  }
  if (i == 0) arr[n] = bsums[gridDim.x];
}

__global__ void scatter_kernel(const int* __restrict__ ei, int* __restrict__ nxt,
                               int* __restrict__ csr_src) {
  int e = blockIdx.x * blockDim.x + threadIdx.x;
  if (e < NEDGES) {
    int s = ei[e];            // src row
    int d = ei[NEDGES + e];   // dst row
    int pos = atomicAdd(&nxt[d], 1);
    csr_src[pos] = s;
  }
}

// ---------------- fused GIN layer ----------------
// R1 structure (256 thr, 4x4 tiles) + single shared LDS buffer (xT/mT/reduction
// time-multiplexed) -> 18.4 KB/block -> 8 blocks/CU (32 waves) instead of 4.
template<int DIN, bool XF>
__global__ __launch_bounds__(256, 8) void gin_kernel(
    const float* __restrict__ X,
    const int* __restrict__ row_ptr, const int* __restrict__ csr_src,
    const float* __restrict__ W1, const float* __restrict__ b1,
    const float* __restrict__ W2, const float* __restrict__ b2,
    const float* __restrict__ scale, const float* __restrict__ shift,
    float* __restrict__ O, float* __restrict__ bn_sum, float* __restrict__ bn_sq) {
  constexpr int R = 32, STR = R + 4;   // pad 36: 16B-aligned b128 reads
  constexpr int KMAX = (DIN > HIDDEN) ? DIN : HIDDEN;
  __shared__ __align__(16) float buf[KMAX * STR];   // xT, then mT, then reduction
  const int t = threadIdx.x;
  const int wv = t >> 6, lane = t & 63;
  const int base = blockIdx.x * R;

  // ---- aggregation: wave handles 8 rows; lane holds features lane, lane+64
  {
    const int f0 = lane, f1 = lane + 64;
    float sc0 = 1.f, sh0 = 0.f, sc1 = 1.f, sh1 = 0.f;
    if (XF) {
      sc0 = scale[f0]; sh0 = shift[f0];
      if (f1 < DIN) { sc1 = scale[f1]; sh1 = shift[f1]; }
    }
    for (int rr = 0; rr < 8; ++rr) {
      const int r = wv * 8 + rr;
      const int node = base + r;
      const float* xr = X + (long)node * DIN;
      float a0 = 0.f, a1 = 0.f;
      {
        float v0 = (f0 < DIN) ? xr[f0] : 0.f;
        if (XF) v0 = relu_f(fmaf(v0, sc0, sh0));
        a0 = v0;
        if (f1 < DIN) {
          float v1 = xr[f1];
          if (XF) v1 = relu_f(fmaf(v1, sc1, sh1));
          a1 = v1;
        }
      }
      const int e0 = row_ptr[node], e1 = row_ptr[node + 1];
      for (int e = e0; e < e1; ++e) {
        const float* xs = X + (long)csr_src[e] * DIN;
        float v0 = (f0 < DIN) ? xs[f0] : 0.f;
        if (XF) v0 = relu_f(fmaf(v0, sc0, sh0));
        a0 += v0;
        if (f1 < DIN) {
          float v1 = xs[f1];
          if (XF) v1 = relu_f(fmaf(v1, sc1, sh1));
          a1 += v1;
        }
      }
      if (f0 < DIN) buf[f0 * STR + r] = a0;
      if (f1 < DIN) buf[f1 * STR + r] = a1;
    }
  }
  __syncthreads();

  const int rg = t >> 5, cg = t & 31;     // 8 row-groups x 32 col-groups
  const int r0 = rg * 4, j0 = cg * 4;     // 4x4 tile per thread

  // ---- mm1: acc = h @ W1 + b1 (keep in regs; buf still holds xT)
  float acc[4][4];
  {
    const float4 bb = *(const float4*)&b1[j0];
    for (int r = 0; r < 4; ++r) { acc[r][0]=bb.x; acc[r][1]=bb.y; acc[r][2]=bb.z; acc[r][3]=bb.w; }
    for (int k = 0; k < DIN; ++k) {
      const float4 w = *(const float4*)&W1[k * HIDDEN + j0];
      const float4 x = *(const float4*)&buf[k * STR + r0];
      const float xa[4] = {x.x, x.y, x.z, x.w};
      const float wa[4] = {w.x, w.y, w.z, w.w};
      for (int r = 0; r < 4; ++r)
        for (int c = 0; c < 4; ++c)
          acc[r][c] = fmaf(xa[r], wa[c], acc[r][c]);
    }
  }
  __syncthreads();   // all xT reads done -> buf reusable as mT

  // ---- write mid = relu(acc) transposed into buf
  for (int c = 0; c < 4; ++c) {
    float4 m = { relu_f(acc[0][c]), relu_f(acc[1][c]), relu_f(acc[2][c]), relu_f(acc[3][c]) };
    *(float4*)&buf[(j0 + c) * STR + r0] = m;
  }
  __syncthreads();

  // ---- mm2: o = mid @ W2 + b2; store pre-BN + BN partials
  float csum[4] = {0,0,0,0}, csq[4] = {0,0,0,0};
  {
    const float4 bb = *(const float4*)&b2[j0];
    for (int r = 0; r < 4; ++r) { acc[r][0]=bb.x; acc[r][1]=bb.y; acc[r][2]=bb.z; acc[r][3]=bb.w; }
    for (int k = 0; k < HIDDEN; ++k) {
      const float4 w = *(const float4*)&W2[k * HIDDEN + j0];
      const float4 x = *(const float4*)&buf[k * STR + r0];
      const float xa[4] = {x.x, x.y, x.z, x.w};
      const float wa[4] = {w.x, w.y, w.z, w.w};
      for (int r = 0; r < 4; ++r)
        for (int c = 0; c < 4; ++c)
          acc[r][c] = fmaf(xa[r], wa[c], acc[r][c]);
    }
    for (int r = 0; r < 4; ++r) {
      float4 o = { acc[r][0], acc[r][1], acc[r][2], acc[r][3] };
      *(float4*)&O[(long)(base + r0 + r) * HIDDEN + j0] = o;
      for (int c = 0; c < 4; ++c) {
        csum[c] += acc[r][c];
        csq[c] = fmaf(acc[r][c], acc[r][c], csq[c]);
      }
    }
  }
  __syncthreads();  // all mm2 reads done -> buf reusable as reduction scratch
  for (int c = 0; c < 4; ++c) {
    buf[(j0 + c) * 8 + rg] = csum[c];
    buf[1024 + (j0 + c) * 8 + rg] = csq[c];
  }
  __syncthreads();
  if (t < HIDDEN) {
    float s = 0.f, q = 0.f;
    for (int g = 0; g < 8; ++g) { s += buf[t * 8 + g]; q += buf[1024 + t * 8 + g]; }
    atomicAdd(&bn_sum[t], s);
    atomicAdd(&bn_sq[t], q);
  }
}

__global__ void bn_finalize_kernel(const float* __restrict__ bn_sum, const float* __restrict__ bn_sq,
                                   const float* __restrict__ g, const float* __restrict__ b,
                                   float* __restrict__ scale, float* __restrict__ shift) {
  int j = threadIdx.x;
  float mu  = bn_sum[j] * (1.0f / NNODES);
  float var = fmaxf(bn_sq[j] * (1.0f / NNODES) - mu * mu, 0.0f);
  float sc  = g[j] / sqrtf(var + 1e-5f);
  scale[j] = sc;
  shift[j] = b[j] - mu * sc;
}

// ---------------- global add pool (with final BN+relu fold) ----------------
__global__ __launch_bounds__(256) void pool_kernel(const float* __restrict__ O,
    const int* __restrict__ gp, const float* __restrict__ scale, const float* __restrict__ shift,
    float* __restrict__ P) {
  int t = threadIdx.x;
  int g = blockIdx.x * 4 + (t >> 6);
  int lane = t & 63;
  int f0 = lane, f1 = lane + 64;
  float sc0 = scale[f0], sh0 = shift[f0], sc1 = scale[f1], sh1 = shift[f1];
  int n0 = gp[g], n1 = gp[g + 1];
  float a0 = 0.f, a1 = 0.f;
  for (int n = n0; n < n1; ++n) {
    a0 += relu_f(fmaf(O[(long)n * HIDDEN + f0], sc0, sh0));
    a1 += relu_f(fmaf(O[(long)n * HIDDEN + f1], sc1, sh1));
  }
  P[g * HIDDEN + f0] = a0;
  P[g * HIDDEN + f1] = a1;
}

// ---------------- protein conv1d(1->32,k=8) + relu + global max ----------------
__global__ __launch_bounds__(256) void conv_kernel(const float* __restrict__ PS,
    const float* __restrict__ CK, const float* __restrict__ CB, float* __restrict__ XP) {
  __shared__ float seq[1000];
  const int t = threadIdx.x, g = blockIdx.x;
  for (int i = t; i < 1000; i += 256) seq[i] = PS[g * 1000 + i];
  __syncthreads();
  const int pl = t & 31, cgp = t >> 5;   // 32 position lanes x 8 channel-groups(4 ch)
  float kr[4][8];
  for (int cc = 0; cc < 4; ++cc)
    for (int k = 0; k < 8; ++k) kr[cc][k] = CK[(cgp * 4 + cc) * 8 + k];
  float m[4] = {-1e30f, -1e30f, -1e30f, -1e30f};
  for (int i = 0; i < 32; ++i) {
    int p = pl + 32 * i;
    if (p < 993) {
      float sv[8];
      for (int k = 0; k < 8; ++k) sv[k] = seq[p + k];
      for (int cc = 0; cc < 4; ++cc) {
        float s = 0.f;
        for (int k = 0; k < 8; ++k) s = fmaf(sv[k], kr[cc][k], s);
        m[cc] = fmaxf(m[cc], s);
      }
    }
  }
  for (int off = 16; off >= 1; off >>= 1)
    for (int cc = 0; cc < 4; ++cc) m[cc] = fmaxf(m[cc], __shfl_xor(m[cc], off));
  if (pl == 0)
    for (int cc = 0; cc < 4; ++cc)
      XP[g * 32 + cgp * 4 + cc] = relu_f(m[cc] + CB[cgp * 4 + cc]);
}

// ---------------- tail gemm: C = relu(A@W + b), 16 rows x 64 cols per block ----------------
template<bool RELU_A>
__global__ __launch_bounds__(256) void gemm2_kernel(const float* __restrict__ A, int lda, int K,
    const float* __restrict__ W, int ldw, const float* __restrict__ bias,
    float* __restrict__ C, int ldc, int coff) {
  constexpr int RT = 16, CH = 64, STR = RT + 4;
  __shared__ __align__(16) float AT[CH * STR];
  const int t = threadIdx.x;
  const int rg = t >> 6, cg = t & 63;
  const int r0 = rg * 4;
  const int row0 = blockIdx.x * RT;
  const int col = blockIdx.y * 64 + cg;
  float a0 = 0.f, a1 = 0.f, a2 = 0.f, a3 = 0.f;
  for (int k0 = 0; k0 < K; k0 += CH) {
    const int kc = min(CH, K - k0);
    __syncthreads();
    for (int i = t; i < RT * CH; i += 256) {
      int kk = i & (CH - 1), r = i >> 6;
      if (kk < kc) {
        float v = A[(long)(row0 + r) * lda + k0 + kk];
        AT[kk * STR + r] = RELU_A ? relu_f(v) : v;
      }
    }
    __syncthreads();
    for (int kk = 0; kk < kc; ++kk) {
      const float4 x = *(const float4*)&AT[kk * STR + r0];
      const float w = W[(long)(k0 + kk) * ldw + col];
      a0 = fmaf(x.x, w, a0);
      a1 = fmaf(x.y, w, a1);
      a2 = fmaf(x.z, w, a2);
      a3 = fmaf(x.w, w, a3);
    }
  }
  const float bv = bias[col];
  C[(long)(row0 + r0 + 0) * ldc + coff + col] = relu_f(a0 + bv);
  C[(long)(row0 + r0 + 1) * ldc + coff + col] = relu_f(a1 + bv);
  C[(long)(row0 + r0 + 2) * ldc + coff + col] = relu_f(a2 + bv);
  C[(long)(row0 + r0 + 3) * ldc + coff + col] = relu_f(a3 + bv);
}

// ---------------- a2h branch: XA init with bias ----------------
__global__ __launch_bounds__(256) void bias_fill_kernel(const float* __restrict__ b,
                                                        float* __restrict__ XA) {
  int i = blockIdx.x * 256 + threadIdx.x;
  XA[i] = b[i & (HIDDEN - 1)];
}

// ---------------- a2h branch split-K gemm: XA += A@W (atomic), pre-relu ----------------
constexpr int A2H_K = 3000, A2H_SPLIT = 300, A2H_NSPLIT = 10;
__global__ __launch_bounds__(128) void a2h_gemm_kernel(const float* __restrict__ A,
    const float* __restrict__ W, float* __restrict__ XA) {
  constexpr int RT = 16, STR = RT + 4;   // LDS tile [300][20]
  __shared__ __align__(16) float xT[A2H_SPLIT * STR];  // 24 KB
  const int t = threadIdx.x;
  const int row0 = blockIdx.x * RT;
  const int k0 = blockIdx.y * A2H_SPLIT;

  constexpr int Q = A2H_SPLIT / 4;       // 75 float4 per row
  for (int i = t; i < RT * Q; i += 128) {
    const int r = i / Q, kq = i - r * Q;
    const float4 v = *(const float4*)&A[(long)(row0 + r) * A2H_K + k0 + kq * 4];
    xT[(kq * 4 + 0) * STR + r] = v.x;
    xT[(kq * 4 + 1) * STR + r] = v.y;
    xT[(kq * 4 + 2) * STR + r] = v.z;
    xT[(kq * 4 + 3) * STR + r] = v.w;
  }
  __syncthreads();

  const int rg = t >> 5, cg = t & 31;    // 4 row-groups x 32 col-groups
  const int r0 = rg * 4, j0 = cg * 4;
  float acc[4][4];
  for (int r = 0; r < 4; ++r)
    for (int c = 0; c < 4; ++c) acc[r][c] = 0.f;

  const float* Wp = W + (long)k0 * HIDDEN + j0;
  for (int k = 0; k < A2H_SPLIT; ++k) {
    const float4 w = *(const float4*)&Wp[(long)k * HIDDEN];
    const float4 x = *(const float4*)&xT[k * STR + r0];
    const float xa[4] = {x.x, x.y, x.z, x.w};
    const float wa[4] = {w.x, w.y, w.z, w.w};
    for (int r = 0; r < 4; ++r)
      for (int c = 0; c < 4; ++c)
        acc[r][c] = fmaf(xa[r], wa[c], acc[r][c]);
  }
  for (int r = 0; r < 4; ++r)
    for (int c = 0; c < 4; ++c)
      atomicAdd(&XA[(long)(row0 + r0 + r) * HIDDEN + j0 + c], acc[r][c]);
}

// ---------------- final projection to scalar ----------------
__global__ __launch_bounds__(256) void final_dot_kernel(const float* __restrict__ X,
    const float* __restrict__ Wo, const float* __restrict__ bo, float* __restrict__ out) {
  int t = threadIdx.x;
  int g = blockIdx.x * 4 + (t >> 6);
  int lane = t & 63;
  float2 x = *(const float2*)&X[g * HIDDEN + lane * 2];
  float2 w = *(const float2*)&Wo[lane * 2];
  float p = x.x * w.x + x.y * w.y;
  for (int off = 32; off >= 1; off >>= 1) p += __shfl_down(p, off);
  if (lane == 0) out[g] = p + bo[0];
}

extern "C" void kernel_launch(void* const* d_in, const int* in_sizes, int n_in,
                              void* d_out, int out_size, void* d_ws, size_t ws_size,
                              hipStream_t stream) {
  const float* x_lig = (const float*)d_in[0];
  const float* pseq  = (const float*)d_in[1];
  const float* a2h   = (const float*)d_in[2];
  const int*   ei    = (const int*)d_in[3];
  const int*   batch = (const int*)d_in[4];
  const float* ginW1[3] = {(const float*)d_in[5],  (const float*)d_in[11], (const float*)d_in[17]};
  const float* ginb1[3] = {(const float*)d_in[6],  (const float*)d_in[12], (const float*)d_in[18]};
  const float* ginW2[3] = {(const float*)d_in[7],  (const float*)d_in[13], (const float*)d_in[19]};
  const float* ginb2[3] = {(const float*)d_in[8],  (const float*)d_in[14], (const float*)d_in[20]};
  const float* bng[3]   = {(const float*)d_in[9],  (const float*)d_in[15], (const float*)d_in[21]};
  const float* bnb[3]   = {(const float*)d_in[10], (const float*)d_in[16], (const float*)d_in[22]};
  const float* ligW  = (const float*)d_in[23]; const float* ligb  = (const float*)d_in[24];
  const float* convk = (const float*)d_in[25]; const float* convb = (const float*)d_in[26];
  const float* protW = (const float*)d_in[27]; const float* protb = (const float*)d_in[28];
  const float* a1W   = (const float*)d_in[29]; const float* a1b   = (const float*)d_in[30];
  const float* a2W   = (const float*)d_in[31]; const float* a2b   = (const float*)d_in[32];
  const float* c1W   = (const float*)d_in[33]; const float* c1b   = (const float*)d_in[34];
  const float* c2W   = (const float*)d_in[35]; const float* c2b   = (const float*)d_in[36];
  const float* oW    = (const float*)d_in[37]; const float* ob    = (const float*)d_in[38];

  char* base = (char*)d_ws;
  size_t off = 0;
  auto alloc = [&](size_t bytes) -> char* {
    char* p = base + off;
    off = (off + bytes + 511) & ~size_t(511);
    return p;
  };
  int*   counts  = (int*)alloc(NNODES * 4);
  int*   gcounts = (int*)alloc(NGRAPHS * 4);
  float* bn_sum  = (float*)alloc(3 * 128 * 4);
  float* bn_sq   = (float*)alloc(3 * 128 * 4);
  const size_t zero_bytes = off;          // counts+gcounts+bn accumulators
  float* bn_scale = (float*)alloc(3 * 128 * 4);
  float* bn_shift = (float*)alloc(3 * 128 * 4);
  int*   row_ptr  = (int*)alloc((NNODES + 1) * 4);
  int*   nxt      = (int*)alloc(NNODES * 4);
  int*   gptr     = (int*)alloc((NGRAPHS + 1) * 4);
  int*   bsumsA   = (int*)alloc(401 * 4);
  int*   bsumsB   = (int*)alloc(9 * 4);
  int*   csr_src  = (int*)alloc(NEDGES * 4);
  float* P        = (float*)alloc(NGRAPHS * 128 * 4);
  float* XA       = (float*)alloc(NGRAPHS * 128 * 4);
  float* XP32     = (float*)alloc(NGRAPHS * 32 * 4);
  float* XC       = (float*)alloc(NGRAPHS * 384 * 4);
  float* XC2      = (float*)alloc(NGRAPHS * 256 * 4);
  float* XC3      = (float*)alloc(NGRAPHS * 128 * 4);
  float* O0       = (float*)alloc((size_t)NNODES * 128 * 4);
  float* O1       = (float*)alloc((size_t)NNODES * 128 * 4);
  (void)ws_size; (void)in_sizes; (void)n_in; (void)out_size;

  hipMemsetAsync(d_ws, 0, zero_bytes, stream);

  // CSR over dst + graph segment ptrs
  hist_kernel<<<(NEDGES + 255) / 256, 256, 0, stream>>>(ei + NEDGES, NEDGES, counts);
  hist_kernel<<<(NNODES + 255) / 256, 256, 0, stream>>>(batch, NNODES, gcounts);
  scan_block_kernel<<<NNODES / 256, 256, 0, stream>>>(counts, NNODES, row_ptr, bsumsA);
  scan_block_kernel<<<NGRAPHS / 256, 256, 0, stream>>>(gcounts, NGRAPHS, gptr, bsumsB);
  scan_top_kernel<<<1, 1024, 0, stream>>>(bsumsA, NNODES / 256);
  scan_top_kernel<<<1, 1024, 0, stream>>>(bsumsB, NGRAPHS / 256);
  scan_add_kernel<<<NNODES / 256, 256, 0, stream>>>(row_ptr, bsumsA, NNODES, nxt);
  scan_add_kernel<<<NGRAPHS / 256, 256, 0, stream>>>(gptr, bsumsB, NGRAPHS, nullptr);
  scatter_kernel<<<(NEDGES + 255) / 256, 256, 0, stream>>>(ei, nxt, csr_src);

  // a2h branch early (independent): bias fill + split-K atomic gemm
  bias_fill_kernel<<<NGRAPHS * HIDDEN / 256, 256, 0, stream>>>(a1b, XA);
  a2h_gemm_kernel<<<dim3(NGRAPHS / 16, A2H_NSPLIT), 128, 0, stream>>>(a2h, a1W, XA);

  // GIN layers (BN+relu of layer l folded into consumer of layer l)
  gin_kernel<78, false><<<NNODES / 32, 256, 0, stream>>>(x_lig, row_ptr, csr_src,
      ginW1[0], ginb1[0], ginW2[0], ginb2[0], nullptr, nullptr, O0, bn_sum, bn_sq);
  bn_finalize_kernel<<<1, 128, 0, stream>>>(bn_sum, bn_sq, bng[0], bnb[0], bn_scale, bn_shift);
  gin_kernel<128, true><<<NNODES / 32, 256, 0, stream>>>(O0, row_ptr, csr_src,
      ginW1[1], ginb1[1], ginW2[1], ginb2[1], bn_scale, bn_shift, O1, bn_sum + 128, bn_sq + 128);
  bn_finalize_kernel<<<1, 128, 0, stream>>>(bn_sum + 128, bn_sq + 128, bng[1], bnb[1],
                                            bn_scale + 128, bn_shift + 128);
  gin_kernel<128, true><<<NNODES / 32, 256, 0, stream>>>(O1, row_ptr, csr_src,
      ginW1[2], ginb1[2], ginW2[2], ginb2[2], bn_scale + 128, bn_shift + 128, O0,
      bn_sum + 256, bn_sq + 256);
  bn_finalize_kernel<<<1, 128, 0, stream>>>(bn_sum + 256, bn_sq + 256, bng[2], bnb[2],
                                            bn_scale + 256, bn_shift + 256);

  // branches
  pool_kernel<<<NGRAPHS / 4, 256, 0, stream>>>(O0, gptr, bn_scale + 256, bn_shift + 256, P);
  conv_kernel<<<NGRAPHS, 256, 0, stream>>>(pseq, convk, convb, XP32);
  gemm2_kernel<false><<<dim3(NGRAPHS / 16, 2), 256, 0, stream>>>(P, 128, 128, ligW, 128, ligb, XC, 384, 0);
  gemm2_kernel<false><<<dim3(NGRAPHS / 16, 2), 256, 0, stream>>>(XP32, 32, 32, protW, 128, protb, XC, 384, 128);
  gemm2_kernel<true><<<dim3(NGRAPHS / 16, 2), 256, 0, stream>>>(XA, 128, 128, a2W, 128, a2b, XC, 384, 256);

  // head
  gemm2_kernel<false><<<dim3(NGRAPHS / 16, 4), 256, 0, stream>>>(XC, 384, 384, c1W, 256, c1b, XC2, 256, 0);
  gemm2_kernel<false><<<dim3(NGRAPHS / 16, 2), 256, 0, stream>>>(XC2, 256, 256, c2W, 128, c2b, XC3, 128, 0);
  final_dot_kernel<<<NGRAPHS / 4, 256, 0, stream>>>(XC3, oW, ob, (float*)d_out);
}